// Round 8
// baseline (253.287 us; speedup 1.0000x reference)
//
#include <hip/hip_runtime.h>
#include <hip/hip_bf16.h>

// MHA block: B=2, L=2048, D=1024, H=16, d_k=64.
// R8: software-pipelined GEMM K-loop — double-buffered As/Bs, prefetch
// issued at iter top (A fp32 loads first so their wait is vmcnt(2), then B
// global_load_lds), compute current, convert+write A regs, ONE barrier per
// iter. R7 showed the 2-barrier K-loop is latency-bound (MfmaUtil 14%,
// VALU 19%, FETCH already minimal): the first barrier ate the full load
// latency every iter. XCD-grouped decode kept. Attention/wtrans/vtrans
// unchanged from R7.

#define D_MODELC 1024
#define N_HEADSC 16
#define D_KC 64
#define BBC 2
#define LLC 2048
#define MMC (BBC * LLC) /* 4096 */

typedef __attribute__((ext_vector_type(8))) short v8s;
typedef __attribute__((ext_vector_type(4))) float v4f;

__device__ __forceinline__ float bf2f(unsigned short u) {
    union { unsigned int i; float f; } x;
    x.i = ((unsigned int)u) << 16;
    return x.f;
}
__device__ __forceinline__ unsigned short f2bf(float f) {
    union { float f; unsigned int i; } x;
    x.f = f;
    unsigned int r = x.i + 0x7fffu + ((x.i >> 16) & 1u);  // RNE
    return (unsigned short)(r >> 16);
}
// packed f32x2 -> bf16x2 (v_cvt_pk_bf16_f32 on gfx950), low short = a
__device__ __forceinline__ unsigned int pk2bf(float a, float b) {
    __hip_bfloat162 h = __float22bfloat162_rn(make_float2(a, b));
    return *(unsigned int*)&h;
}

#define AS1 __attribute__((address_space(1)))
#define AS3 __attribute__((address_space(3)))

// ---------------- weight transpose+convert: Wt[z][n][k] = W_z[k][n] ----------------
__global__ __launch_bounds__(256) void wtrans(const float* __restrict__ w0,
                                              const float* __restrict__ w1,
                                              const float* __restrict__ w2,
                                              const float* __restrict__ w3,
                                              unsigned short* __restrict__ out) {
    __shared__ unsigned short T[64][65];
    const int z = blockIdx.z;
    const float* W = z == 0 ? w0 : (z == 1 ? w1 : (z == 2 ? w2 : w3));
    unsigned short* O = out + (size_t)z * D_MODELC * D_MODELC;
    const int k0 = blockIdx.y * 64, n0 = blockIdx.x * 64;
    const int c = threadIdx.x & 63, r4 = threadIdx.x >> 6;
#pragma unroll
    for (int i = 0; i < 16; i++) {
        int r = i * 4 + r4;
        T[r][c] = f2bf(W[(size_t)(k0 + r) * D_MODELC + n0 + c]);
    }
    __syncthreads();
#pragma unroll
    for (int i = 0; i < 16; i++) {
        int r = i * 4 + r4;
        O[(size_t)(n0 + r) * D_MODELC + k0 + c] = T[c][r];
    }
}

// ---------------- V transpose: Vt[bh][d][L] = Vp[b*L + j][h*64 + d] ----------------
__global__ __launch_bounds__(256) void vtrans(const unsigned short* __restrict__ Vp,
                                              unsigned short* __restrict__ Vt) {
    __shared__ __align__(16) unsigned short T[64][68];
    const int bh = blockIdx.y;
    const int b = bh >> 4, h = bh & 15;
    const int j0 = blockIdx.x * 64;
    const int t = threadIdx.x;
#pragma unroll
    for (int i = 0; i < 2; i++) {
        int c = i * 256 + t;
        int row = c >> 3, ch = c & 7;
        *(v8s*)&T[row][ch * 8] =
            *(const v8s*)&Vp[((size_t)(b * LLC + j0 + row)) * D_MODELC + h * 64 + ch * 8];
    }
    __syncthreads();
#pragma unroll
    for (int i = 0; i < 2; i++) {
        int c = i * 256 + t;
        int drow = c >> 3, jch = c & 7;
        v8s pk;
#pragma unroll
        for (int u = 0; u < 8; u++) pk[u] = (short)T[jch * 8 + u][drow];
        *(v8s*)&Vt[((size_t)bh * 64 + drow) * LLC + j0 + jch * 8] = pk;
    }
}

// ---------------- pipelined GEMM with XCD-grouped block decode ----------------
template <int MT, int SEGS, bool A_F32, bool OUT_F32>
__global__ __launch_bounds__(256) void gemm_tile(
    const void* __restrict__ A0, const void* __restrict__ A1, const void* __restrict__ A2,
    const unsigned short* __restrict__ Wt,
    const float* __restrict__ bias0, const float* __restrict__ bias1,
    const float* __restrict__ bias2,
    void* __restrict__ C0, void* __restrict__ C1, void* __restrict__ C2,
    float scale0, float scale1, float scale2) {
    const int K = D_MODELC, N = D_MODELC;
    constexpr int MI = MT / 32;         // MFMA row-tiles per wave
    constexpr int MB = MMC / MT;        // m-tiles
    constexpr int PER = SEGS * MB / 8;  // groups per XCD
    __shared__ __align__(16) unsigned short As[2][MT * 32];
    __shared__ __align__(16) unsigned short Bs[2][128 * 32];

    const int t = threadIdx.x;
    const int w = t >> 6, lane = t & 63;
    const int quad = lane >> 4, m15 = lane & 15;
    const int wr = w >> 1, wc = w & 1;

    // XCD-grouped decode (8 n-blocks of one (seg,mb) share blockIdx%8)
    const int flat = blockIdx.x;
    const int xcd = flat & 7;
    const int slot = flat >> 3;
    const int group = xcd * PER + (slot >> 3);
    const int nb = slot & 7;
    const int seg = group / MB;
    const int mb = group % MB;
    const int n0 = nb * 128;
    const int m0 = mb * MT;

    const void* Ap = seg == 0 ? A0 : (seg == 1 ? A1 : A2);
    const unsigned short* Wp = Wt + (size_t)seg * D_MODELC * D_MODELC;
    const float* bias = seg == 0 ? bias0 : (seg == 1 ? bias1 : bias2);
    void* Cp = seg == 0 ? C0 : (seg == 1 ? C1 : C2);
    const float scl = seg == 0 ? scale0 : (seg == 1 ? scale1 : scale2);

    float4 fa[MT / 64][2];  // in-flight fp32 A regs (A_F32 path)

    // issue fp32 A loads for k-slice k0 (issued BEFORE B so the A-wait
    // leaves B's global_load_lds in flight)
    auto loadA = [&](int k0) {
#pragma unroll
        for (int i = 0; i < MT / 64; i++) {
            int c = i * 256 + t;
            int row = c >> 2, cc = (c & 3) * 8;
            const float* src = (const float*)Ap + (size_t)(m0 + row) * K + k0 + cc;
            fa[i][0] = ((const float4*)src)[0];
            fa[i][1] = ((const float4*)src)[1];
        }
    };
    auto convA = [&](int buf) {
#pragma unroll
        for (int i = 0; i < MT / 64; i++) {
            int c = i * 256 + t;
            uint4 pk;
            pk.x = pk2bf(fa[i][0].x, fa[i][0].y);
            pk.y = pk2bf(fa[i][0].z, fa[i][0].w);
            pk.z = pk2bf(fa[i][1].x, fa[i][1].y);
            pk.w = pk2bf(fa[i][1].z, fa[i][1].w);
            *(uint4*)&As[buf][c * 8] = pk;
        }
    };
    auto stageB = [&](int k0, int buf) {
#pragma unroll
        for (int i = 0; i < 2; i++) {
            int c = i * 256 + t;
            int row = c >> 2, cc = (c & 3) * 8;
            const unsigned short* g = Wp + (size_t)(n0 + row) * K + k0 + cc;
            __builtin_amdgcn_global_load_lds(
                (const AS1 unsigned int*)g,
                (AS3 unsigned int*)(&Bs[buf][0] + i * 2048 + w * 512), 16, 0, 0);
        }
    };
    auto stageA_async = [&](int k0, int buf) {
#pragma unroll
        for (int i = 0; i < MT / 64; i++) {
            int c = i * 256 + t;
            int row = c >> 2, cc = (c & 3) * 8;
            const unsigned short* g =
                (const unsigned short*)Ap + (size_t)(m0 + row) * K + k0 + cc;
            __builtin_amdgcn_global_load_lds(
                (const AS1 unsigned int*)g,
                (AS3 unsigned int*)(&As[buf][0] + i * 2048 + w * 512), 16, 0, 0);
        }
    };

    v4f acc[MI][4];
#pragma unroll
    for (int mi = 0; mi < MI; mi++)
#pragma unroll
        for (int ni = 0; ni < 4; ni++) acc[mi][ni] = (v4f){0.f, 0.f, 0.f, 0.f};

    // prologue: stage k-slice 0 into buffer 0
    if (A_F32) loadA(0);
    stageB(0, 0);
    if (A_F32) convA(0); else stageA_async(0, 0);
    __syncthreads();

    for (int it = 0; it < K / 32; it++) {
        const int cur = it & 1;
        const bool more = it < K / 32 - 1;
        if (more) {
            if (A_F32) loadA((it + 1) * 32);       // fp32 A first (vmcnt order)
            stageB((it + 1) * 32, cur ^ 1);        // async direct-to-LDS
            if (!A_F32) stageA_async((it + 1) * 32, cur ^ 1);
        }

        v8s a[MI], bfr[4];
#pragma unroll
        for (int mi = 0; mi < MI; mi++)
            a[mi] = *(const v8s*)&As[cur][(wr * (MT / 2) + mi * 16 + m15) * 32 + quad * 8];
#pragma unroll
        for (int ni = 0; ni < 4; ni++)
            bfr[ni] = *(const v8s*)&Bs[cur][(wc * 64 + ni * 16 + m15) * 32 + quad * 8];
#pragma unroll
        for (int mi = 0; mi < MI; mi++)
#pragma unroll
            for (int ni = 0; ni < 4; ni++)
                acc[mi][ni] =
                    __builtin_amdgcn_mfma_f32_16x16x32_bf16(a[mi], bfr[ni], acc[mi][ni], 0, 0, 0);

        // A regs -> LDS for next iter (their loads flew during the MFMAs)
        if (more && A_F32) convA(cur ^ 1);
        __syncthreads();  // drains prefetch vmcnt + closes buffer reads
    }

#pragma unroll
    for (int ni = 0; ni < 4; ni++) {
        int col = n0 + wc * 64 + ni * 16 + m15;
        float bv = bias[col];
#pragma unroll
        for (int mi = 0; mi < MI; mi++) {
#pragma unroll
            for (int r = 0; r < 4; r++) {
                int row = m0 + wr * (MT / 2) + mi * 16 + quad * 4 + r;
                float v = (acc[mi][ni][r] + bv) * scl;
                if (OUT_F32)
                    ((float*)Cp)[(size_t)row * N + col] = v;
                else
                    ((unsigned short*)Cp)[(size_t)row * N + col] = f2bf(v);
            }
        }
    }
}

// ---------------- MFMA flash attention (unchanged from R7) ----------------
__global__ __launch_bounds__(256) void attn_mfma(const unsigned short* __restrict__ Qp,
                                                 const unsigned short* __restrict__ Kp,
                                                 const unsigned short* __restrict__ Vt,
                                                 unsigned short* __restrict__ X) {
    __shared__ __align__(16) unsigned short lds[8192 + 8192 + 128 * 72];
    unsigned short* Kb = lds;
    unsigned short* Vb = lds + 8192;
    unsigned short* PQ = lds + 16384;

    const int t = threadIdx.x;
    const int w = t >> 6, lane = t & 63;
    const int quad = lane >> 4, m15 = lane & 15;
    const int bh = blockIdx.y;
    const int b = bh >> 4, h = bh & 15;
    const int q0 = blockIdx.x * 128;
    const size_t hd = (size_t)h * 64;
    const int sw = m15 & 7;

#pragma unroll
    for (int i = 0; i < 4; i++) {
        int chunk = i * 256 + t;
        int row = chunk >> 3, slot = chunk & 7;
        int j = slot ^ (row & 7);
        const unsigned short* g =
            Qp + ((size_t)(b * LLC + q0 + row)) * D_MODELC + hd + j * 8;
        __builtin_amdgcn_global_load_lds((const AS1 unsigned int*)g,
                                         (AS3 unsigned int*)(PQ + (i * 256 + w * 64) * 8),
                                         16, 0, 0);
    }
    {
#pragma unroll
        for (int i = 0; i < 2; i++) {
            int chunk = i * 256 + t;
            int row = chunk >> 3, slot = chunk & 7;
            int j = slot ^ (row & 7);
            int gr = 4 * (row & 15) + (row >> 4);  // sigma
            const unsigned short* g =
                Kp + ((size_t)(b * LLC + 0 + gr)) * D_MODELC + hd + j * 8;
            __builtin_amdgcn_global_load_lds((const AS1 unsigned int*)g,
                                             (AS3 unsigned int*)(Kb + (i * 256 + w * 64) * 8),
                                             16, 0, 0);
        }
#pragma unroll
        for (int i = 0; i < 2; i++) {
            int chunk = i * 256 + t;
            int row = chunk >> 3, slot = chunk & 7;
            int j = slot ^ (row & 7);
            const unsigned short* g = Vt + ((size_t)(bh * 64 + row)) * LLC + 0 + j * 8;
            __builtin_amdgcn_global_load_lds((const AS1 unsigned int*)g,
                                             (AS3 unsigned int*)(Vb + (i * 256 + w * 64) * 8),
                                             16, 0, 0);
        }
    }
    __syncthreads();

    v8s qa[2][2];
#pragma unroll
    for (int mi = 0; mi < 2; mi++)
#pragma unroll
        for (int kk = 0; kk < 2; kk++)
            qa[mi][kk] = *(const v8s*)&PQ[(w * 32 + mi * 16 + m15) * 64 +
                                          (((kk * 4 + quad) ^ sw) * 8)];
    __syncthreads();

    v8s ones;
#pragma unroll
    for (int u = 0; u < 8; u++) ones[u] = (short)0x3F80;  // bf16 1.0

    v4f O[2][4];
#pragma unroll
    for (int mi = 0; mi < 2; mi++)
#pragma unroll
        for (int db = 0; db < 4; db++) O[mi][db] = (v4f){0.f, 0.f, 0.f, 0.f};
    v4f lacc[2] = {(v4f){0.f, 0.f, 0.f, 0.f}, (v4f){0.f, 0.f, 0.f, 0.f}};

    for (int it = 0; it < 32; it++) {
        const int cur = it & 1;
        unsigned short* Kc = Kb + cur * 4096;
        unsigned short* Vc = Vb + cur * 4096;
        if (it < 31) {
            unsigned short* Kn = Kb + (cur ^ 1) * 4096;
            unsigned short* Vn = Vb + (cur ^ 1) * 4096;
            const int k0n = (it + 1) * 64;
#pragma unroll
            for (int i = 0; i < 2; i++) {
                int chunk = i * 256 + t;
                int row = chunk >> 3, slot = chunk & 7;
                int j = slot ^ (row & 7);
                int gr = 4 * (row & 15) + (row >> 4);
                const unsigned short* g =
                    Kp + ((size_t)(b * LLC + k0n + gr)) * D_MODELC + hd + j * 8;
                __builtin_amdgcn_global_load_lds(
                    (const AS1 unsigned int*)g,
                    (AS3 unsigned int*)(Kn + (i * 256 + w * 64) * 8), 16, 0, 0);
            }
#pragma unroll
            for (int i = 0; i < 2; i++) {
                int chunk = i * 256 + t;
                int row = chunk >> 3, slot = chunk & 7;
                int j = slot ^ (row & 7);
                const unsigned short* g =
                    Vt + ((size_t)(bh * 64 + row)) * LLC + k0n + j * 8;
                __builtin_amdgcn_global_load_lds(
                    (const AS1 unsigned int*)g,
                    (AS3 unsigned int*)(Vn + (i * 256 + w * 64) * 8), 16, 0, 0);
            }
        }

        v4f S[2][4];
#pragma unroll
        for (int mi = 0; mi < 2; mi++)
#pragma unroll
            for (int ns = 0; ns < 4; ns++) S[mi][ns] = (v4f){0.f, 0.f, 0.f, 0.f};
#pragma unroll
        for (int kk = 0; kk < 2; kk++) {
#pragma unroll
            for (int ns = 0; ns < 4; ns++) {
                v8s kf = *(const v8s*)&Kc[(ns * 16 + m15) * 64 +
                                          (((kk * 4 + quad) ^ sw) * 8)];
#pragma unroll
                for (int mi = 0; mi < 2; mi++)
                    S[mi][ns] =
                        __builtin_amdgcn_mfma_f32_16x16x32_bf16(qa[mi][kk], kf, S[mi][ns], 0, 0, 0);
            }
        }

#pragma unroll
        for (int mi = 0; mi < 2; mi++) {
#pragma unroll
            for (int r = 0; r < 4; r++) {
                int prow = w * 32 + mi * 16 + quad * 4 + r;
                float e0 = __builtin_amdgcn_exp2f(S[mi][0][r]);
                float e1 = __builtin_amdgcn_exp2f(S[mi][1][r]);
                float e2 = __builtin_amdgcn_exp2f(S[mi][2][r]);
                float e3 = __builtin_amdgcn_exp2f(S[mi][3][r]);
                uint2 pk;
                pk.x = pk2bf(e0, e1);
                pk.y = pk2bf(e2, e3);
                *(uint2*)&PQ[prow * 72 + 4 * m15] = pk;
            }
        }

#pragma unroll
        for (int kk = 0; kk < 2; kk++) {
            v8s a0 = *(const v8s*)&PQ[(w * 32 + 0 * 16 + m15) * 72 + kk * 32 + quad * 8];
            v8s a1 = *(const v8s*)&PQ[(w * 32 + 1 * 16 + m15) * 72 + kk * 32 + quad * 8];
            lacc[0] = __builtin_amdgcn_mfma_f32_16x16x32_bf16(a0, ones, lacc[0], 0, 0, 0);
            lacc[1] = __builtin_amdgcn_mfma_f32_16x16x32_bf16(a1, ones, lacc[1], 0, 0, 0);
#pragma unroll
            for (int db = 0; db < 4; db++) {
                v8s vf = *(const v8s*)&Vc[(db * 16 + m15) * 64 +
                                          (((kk * 4 + quad) ^ sw) * 8)];
                O[0][db] = __builtin_amdgcn_mfma_f32_16x16x32_bf16(a0, vf, O[0][db], 0, 0, 0);
                O[1][db] = __builtin_amdgcn_mfma_f32_16x16x32_bf16(a1, vf, O[1][db], 0, 0, 0);
            }
        }
        __syncthreads();
    }

#pragma unroll
    for (int mi = 0; mi < 2; mi++) {
#pragma unroll
        for (int r = 0; r < 4; r++) {
            float inv = 1.f / lacc[mi][r];
            int row = q0 + w * 32 + mi * 16 + quad * 4 + r;
#pragma unroll
            for (int db = 0; db < 4; db++) {
                X[((size_t)(b * LLC + row)) * D_MODELC + hd + db * 16 + m15] =
                    f2bf(O[mi][db][r] * inv);
            }
        }
    }
}

extern "C" void kernel_launch(void* const* d_in, const int* in_sizes, int n_in,
                              void* d_out, int out_size, void* d_ws, size_t ws_size,
                              hipStream_t stream) {
    const float* q = (const float*)d_in[0];
    const float* k = (const float*)d_in[1];
    const float* v = (const float*)d_in[2];
    const float* w_q = (const float*)d_in[3];
    const float* b_q = (const float*)d_in[4];
    const float* w_k = (const float*)d_in[5];
    const float* b_k = (const float*)d_in[6];
    const float* w_v = (const float*)d_in[7];
    const float* b_v = (const float*)d_in[8];
    const float* w_o = (const float*)d_in[9];
    const float* b_o = (const float*)d_in[10];

    const size_t elems = (size_t)MMC * D_MODELC;  // 4M elems = 8MB bf16
    unsigned short* Qp = (unsigned short*)d_ws;   // X aliases Qp (see attn)
    unsigned short* Kp = Qp + elems;
    unsigned short* Vp = Kp + elems;
    unsigned short* Wt = Vp + elems;  // 4 x 1024x1024 bf16 = 8MB (q,k,v,o)
    unsigned short* X = Qp;
    unsigned short* Vt = (unsigned short*)d_out;  // scratch until final GEMM

    const float QSCALE = 0.125f * 1.44269504088896340736f;  // 1/sqrt(64)*log2(e)

    wtrans<<<dim3(16, 16, 4), 256, 0, stream>>>(w_q, w_k, w_v, w_o, Wt);

    // QKV: 3 segs x 32 m-tiles x 8 n-blocks = 768 blocks, XCD-grouped decode
    gemm_tile<128, 3, true, false><<<768, 256, 0, stream>>>(
        q, k, v, Wt, b_q, b_k, b_v, Qp, Kp, Vp, QSCALE, 1.f, 1.f);

    vtrans<<<dim3(LLC / 64, BBC * N_HEADSC), 256, 0, stream>>>(Vp, Vt);

    attn_mfma<<<dim3(LLC / 128, BBC * N_HEADSC), 256, 0, stream>>>(Qp, Kp, Vt, X);

    // final: 1 seg x 64 m-tiles x 8 n-blocks = 512 blocks
    gemm_tile<64, 1, false, true><<<512, 256, 0, stream>>>(
        X, X, X, Wt + (size_t)3 * D_MODELC * D_MODELC, b_o, b_o, b_o,
        d_out, d_out, d_out, 1.f, 1.f, 1.f);
}

// Round 9
// 243.281 us; speedup vs baseline: 1.0411x; 1.0411x over previous
//
#include <hip/hip_runtime.h>
#include <hip/hip_bf16.h>

// MHA block: B=2, L=2048, D=1024, H=16, d_k=64.
// R9: revert R8 pipelining (barrier drains its own prefetch — regressed).
// Back to R7's 2-barrier K-loop but with BK=64: 32 MFMA per barrier instead
// of 16, 16 iters instead of 32, LDS 32KB single-buffered. 128B-stride rows
// use the attention-validated XOR chunk swizzle (global side swizzled, LDS
// linear) to stay conflict-free. XCD-grouped decode kept. Attention /
// wtrans / vtrans byte-identical to R7.

#define D_MODELC 1024
#define N_HEADSC 16
#define D_KC 64
#define BBC 2
#define LLC 2048
#define MMC (BBC * LLC) /* 4096 */

typedef __attribute__((ext_vector_type(8))) short v8s;
typedef __attribute__((ext_vector_type(4))) float v4f;

__device__ __forceinline__ float bf2f(unsigned short u) {
    union { unsigned int i; float f; } x;
    x.i = ((unsigned int)u) << 16;
    return x.f;
}
__device__ __forceinline__ unsigned short f2bf(float f) {
    union { float f; unsigned int i; } x;
    x.f = f;
    unsigned int r = x.i + 0x7fffu + ((x.i >> 16) & 1u);  // RNE
    return (unsigned short)(r >> 16);
}
// packed f32x2 -> bf16x2 (v_cvt_pk_bf16_f32 on gfx950), low short = a
__device__ __forceinline__ unsigned int pk2bf(float a, float b) {
    __hip_bfloat162 h = __float22bfloat162_rn(make_float2(a, b));
    return *(unsigned int*)&h;
}

#define AS1 __attribute__((address_space(1)))
#define AS3 __attribute__((address_space(3)))

// ---------------- weight transpose+convert: Wt[z][n][k] = W_z[k][n] ----------------
__global__ __launch_bounds__(256) void wtrans(const float* __restrict__ w0,
                                              const float* __restrict__ w1,
                                              const float* __restrict__ w2,
                                              const float* __restrict__ w3,
                                              unsigned short* __restrict__ out) {
    __shared__ unsigned short T[64][65];
    const int z = blockIdx.z;
    const float* W = z == 0 ? w0 : (z == 1 ? w1 : (z == 2 ? w2 : w3));
    unsigned short* O = out + (size_t)z * D_MODELC * D_MODELC;
    const int k0 = blockIdx.y * 64, n0 = blockIdx.x * 64;
    const int c = threadIdx.x & 63, r4 = threadIdx.x >> 6;
#pragma unroll
    for (int i = 0; i < 16; i++) {
        int r = i * 4 + r4;
        T[r][c] = f2bf(W[(size_t)(k0 + r) * D_MODELC + n0 + c]);
    }
    __syncthreads();
#pragma unroll
    for (int i = 0; i < 16; i++) {
        int r = i * 4 + r4;
        O[(size_t)(n0 + r) * D_MODELC + k0 + c] = T[c][r];
    }
}

// ---------------- V transpose: Vt[bh][d][L] = Vp[b*L + j][h*64 + d] ----------------
__global__ __launch_bounds__(256) void vtrans(const unsigned short* __restrict__ Vp,
                                              unsigned short* __restrict__ Vt) {
    __shared__ __align__(16) unsigned short T[64][68];
    const int bh = blockIdx.y;
    const int b = bh >> 4, h = bh & 15;
    const int j0 = blockIdx.x * 64;
    const int t = threadIdx.x;
#pragma unroll
    for (int i = 0; i < 2; i++) {
        int c = i * 256 + t;
        int row = c >> 3, ch = c & 7;
        *(v8s*)&T[row][ch * 8] =
            *(const v8s*)&Vp[((size_t)(b * LLC + j0 + row)) * D_MODELC + h * 64 + ch * 8];
    }
    __syncthreads();
#pragma unroll
    for (int i = 0; i < 2; i++) {
        int c = i * 256 + t;
        int drow = c >> 3, jch = c & 7;
        v8s pk;
#pragma unroll
        for (int u = 0; u < 8; u++) pk[u] = (short)T[jch * 8 + u][drow];
        *(v8s*)&Vt[((size_t)bh * 64 + drow) * LLC + j0 + jch * 8] = pk;
    }
}

// ---------------- BK=64 GEMM, 2-barrier K-loop, XCD-grouped decode ----------------
// LDS rows are 64 shorts (128B); chunk j of row r lives at slot j^(r&7)
// (swizzle applied on the GLOBAL address for async staging; ds_write path
// writes the swizzled slot directly). Frag reads XOR with sw = m15&7.
template <int MT, int SEGS, bool A_F32, bool OUT_F32>
__global__ __launch_bounds__(256) void gemm_tile(
    const void* __restrict__ A0, const void* __restrict__ A1, const void* __restrict__ A2,
    const unsigned short* __restrict__ Wt,
    const float* __restrict__ bias0, const float* __restrict__ bias1,
    const float* __restrict__ bias2,
    void* __restrict__ C0, void* __restrict__ C1, void* __restrict__ C2,
    float scale0, float scale1, float scale2) {
    const int K = D_MODELC, N = D_MODELC;
    constexpr int MI = MT / 32;         // MFMA row-tiles per wave
    constexpr int MB = MMC / MT;        // m-tiles
    constexpr int PER = SEGS * MB / 8;  // groups per XCD
    __shared__ __align__(16) unsigned short As[MT * 64];
    __shared__ __align__(16) unsigned short Bs[128 * 64];

    const int t = threadIdx.x;
    const int w = t >> 6, lane = t & 63;
    const int quad = lane >> 4, m15 = lane & 15;
    const int wr = w >> 1, wc = w & 1;
    const int sw = m15 & 7;

    // XCD-grouped decode (8 n-blocks of one (seg,mb) share blockIdx%8)
    const int flat = blockIdx.x;
    const int xcd = flat & 7;
    const int slot0 = flat >> 3;
    const int group = xcd * PER + (slot0 >> 3);
    const int nb = slot0 & 7;
    const int seg = group / MB;
    const int mb = group % MB;
    const int n0 = nb * 128;
    const int m0 = mb * MT;

    const void* Ap = seg == 0 ? A0 : (seg == 1 ? A1 : A2);
    const unsigned short* Wp = Wt + (size_t)seg * D_MODELC * D_MODELC;
    const float* bias = seg == 0 ? bias0 : (seg == 1 ? bias1 : bias2);
    void* Cp = seg == 0 ? C0 : (seg == 1 ? C1 : C2);
    const float scl = seg == 0 ? scale0 : (seg == 1 ? scale1 : scale2);

    v4f acc[MI][4];
#pragma unroll
    for (int mi = 0; mi < MI; mi++)
#pragma unroll
        for (int ni = 0; ni < 4; ni++) acc[mi][ni] = (v4f){0.f, 0.f, 0.f, 0.f};

    for (int k0 = 0; k0 < K; k0 += 64) {
        // B staging: 128 rows x 8 chunks, 4 chunks/thread, async.
        // LDS linear (wave base + lane*16), global chunk = slot ^ (row&7).
#pragma unroll
        for (int i = 0; i < 4; i++) {
            int c = i * 256 + t;
            int row = c >> 3, slot = c & 7;
            int j = slot ^ (row & 7);
            const unsigned short* g = Wp + (size_t)(n0 + row) * K + k0 + j * 8;
            __builtin_amdgcn_global_load_lds(
                (const AS1 unsigned int*)g,
                (AS3 unsigned int*)(Bs + (size_t)c * 8), 16, 0, 0);
        }
        if (A_F32) {
            // fp32 A: vector loads + packed convert + swizzled ds_write
#pragma unroll
            for (int i = 0; i < MT / 32; i++) {
                int c = i * 256 + t;
                int row = c >> 3, slot = c & 7;
                int j = slot ^ (row & 7);
                const float* src = (const float*)Ap + (size_t)(m0 + row) * K + k0 + j * 8;
                float4 f0 = ((const float4*)src)[0];
                float4 f1 = ((const float4*)src)[1];
                uint4 pk;
                pk.x = pk2bf(f0.x, f0.y);
                pk.y = pk2bf(f0.z, f0.w);
                pk.z = pk2bf(f1.x, f1.y);
                pk.w = pk2bf(f1.z, f1.w);
                *(uint4*)&As[(size_t)c * 8] = pk;
            }
        } else {
#pragma unroll
            for (int i = 0; i < MT / 32; i++) {
                int c = i * 256 + t;
                int row = c >> 3, slot = c & 7;
                int j = slot ^ (row & 7);
                const unsigned short* g =
                    (const unsigned short*)Ap + (size_t)(m0 + row) * K + k0 + j * 8;
                __builtin_amdgcn_global_load_lds(
                    (const AS1 unsigned int*)g,
                    (AS3 unsigned int*)(As + (size_t)c * 8), 16, 0, 0);
            }
        }
        __syncthreads();

#pragma unroll
        for (int kk = 0; kk < 2; kk++) {
            v8s a[MI], bfr[4];
#pragma unroll
            for (int mi = 0; mi < MI; mi++)
                a[mi] = *(const v8s*)&As[(wr * (MT / 2) + mi * 16 + m15) * 64 +
                                         (((kk * 4 + quad) ^ sw) * 8)];
#pragma unroll
            for (int ni = 0; ni < 4; ni++)
                bfr[ni] = *(const v8s*)&Bs[(wc * 64 + ni * 16 + m15) * 64 +
                                           (((kk * 4 + quad) ^ sw) * 8)];
#pragma unroll
            for (int mi = 0; mi < MI; mi++)
#pragma unroll
                for (int ni = 0; ni < 4; ni++)
                    acc[mi][ni] = __builtin_amdgcn_mfma_f32_16x16x32_bf16(
                        a[mi], bfr[ni], acc[mi][ni], 0, 0, 0);
        }
        __syncthreads();
    }

#pragma unroll
    for (int ni = 0; ni < 4; ni++) {
        int col = n0 + wc * 64 + ni * 16 + m15;
        float bv = bias[col];
#pragma unroll
        for (int mi = 0; mi < MI; mi++) {
#pragma unroll
            for (int r = 0; r < 4; r++) {
                int row = m0 + wr * (MT / 2) + mi * 16 + quad * 4 + r;
                float v = (acc[mi][ni][r] + bv) * scl;
                if (OUT_F32)
                    ((float*)Cp)[(size_t)row * N + col] = v;
                else
                    ((unsigned short*)Cp)[(size_t)row * N + col] = f2bf(v);
            }
        }
    }
}

// ---------------- MFMA flash attention (unchanged from R7) ----------------
__global__ __launch_bounds__(256) void attn_mfma(const unsigned short* __restrict__ Qp,
                                                 const unsigned short* __restrict__ Kp,
                                                 const unsigned short* __restrict__ Vt,
                                                 unsigned short* __restrict__ X) {
    __shared__ __align__(16) unsigned short lds[8192 + 8192 + 128 * 72];
    unsigned short* Kb = lds;
    unsigned short* Vb = lds + 8192;
    unsigned short* PQ = lds + 16384;

    const int t = threadIdx.x;
    const int w = t >> 6, lane = t & 63;
    const int quad = lane >> 4, m15 = lane & 15;
    const int bh = blockIdx.y;
    const int b = bh >> 4, h = bh & 15;
    const int q0 = blockIdx.x * 128;
    const size_t hd = (size_t)h * 64;
    const int sw = m15 & 7;

#pragma unroll
    for (int i = 0; i < 4; i++) {
        int chunk = i * 256 + t;
        int row = chunk >> 3, slot = chunk & 7;
        int j = slot ^ (row & 7);
        const unsigned short* g =
            Qp + ((size_t)(b * LLC + q0 + row)) * D_MODELC + hd + j * 8;
        __builtin_amdgcn_global_load_lds((const AS1 unsigned int*)g,
                                         (AS3 unsigned int*)(PQ + (i * 256 + w * 64) * 8),
                                         16, 0, 0);
    }
    {
#pragma unroll
        for (int i = 0; i < 2; i++) {
            int chunk = i * 256 + t;
            int row = chunk >> 3, slot = chunk & 7;
            int j = slot ^ (row & 7);
            int gr = 4 * (row & 15) + (row >> 4);  // sigma
            const unsigned short* g =
                Kp + ((size_t)(b * LLC + 0 + gr)) * D_MODELC + hd + j * 8;
            __builtin_amdgcn_global_load_lds((const AS1 unsigned int*)g,
                                             (AS3 unsigned int*)(Kb + (i * 256 + w * 64) * 8),
                                             16, 0, 0);
        }
#pragma unroll
        for (int i = 0; i < 2; i++) {
            int chunk = i * 256 + t;
            int row = chunk >> 3, slot = chunk & 7;
            int j = slot ^ (row & 7);
            const unsigned short* g = Vt + ((size_t)(bh * 64 + row)) * LLC + 0 + j * 8;
            __builtin_amdgcn_global_load_lds((const AS1 unsigned int*)g,
                                             (AS3 unsigned int*)(Vb + (i * 256 + w * 64) * 8),
                                             16, 0, 0);
        }
    }
    __syncthreads();

    v8s qa[2][2];
#pragma unroll
    for (int mi = 0; mi < 2; mi++)
#pragma unroll
        for (int kk = 0; kk < 2; kk++)
            qa[mi][kk] = *(const v8s*)&PQ[(w * 32 + mi * 16 + m15) * 64 +
                                          (((kk * 4 + quad) ^ sw) * 8)];
    __syncthreads();

    v8s ones;
#pragma unroll
    for (int u = 0; u < 8; u++) ones[u] = (short)0x3F80;  // bf16 1.0

    v4f O[2][4];
#pragma unroll
    for (int mi = 0; mi < 2; mi++)
#pragma unroll
        for (int db = 0; db < 4; db++) O[mi][db] = (v4f){0.f, 0.f, 0.f, 0.f};
    v4f lacc[2] = {(v4f){0.f, 0.f, 0.f, 0.f}, (v4f){0.f, 0.f, 0.f, 0.f}};

    for (int it = 0; it < 32; it++) {
        const int cur = it & 1;
        unsigned short* Kc = Kb + cur * 4096;
        unsigned short* Vc = Vb + cur * 4096;
        if (it < 31) {
            unsigned short* Kn = Kb + (cur ^ 1) * 4096;
            unsigned short* Vn = Vb + (cur ^ 1) * 4096;
            const int k0n = (it + 1) * 64;
#pragma unroll
            for (int i = 0; i < 2; i++) {
                int chunk = i * 256 + t;
                int row = chunk >> 3, slot = chunk & 7;
                int j = slot ^ (row & 7);
                int gr = 4 * (row & 15) + (row >> 4);
                const unsigned short* g =
                    Kp + ((size_t)(b * LLC + k0n + gr)) * D_MODELC + hd + j * 8;
                __builtin_amdgcn_global_load_lds(
                    (const AS1 unsigned int*)g,
                    (AS3 unsigned int*)(Kn + (i * 256 + w * 64) * 8), 16, 0, 0);
            }
#pragma unroll
            for (int i = 0; i < 2; i++) {
                int chunk = i * 256 + t;
                int row = chunk >> 3, slot = chunk & 7;
                int j = slot ^ (row & 7);
                const unsigned short* g =
                    Vt + ((size_t)(bh * 64 + row)) * LLC + k0n + j * 8;
                __builtin_amdgcn_global_load_lds(
                    (const AS1 unsigned int*)g,
                    (AS3 unsigned int*)(Vn + (i * 256 + w * 64) * 8), 16, 0, 0);
            }
        }

        v4f S[2][4];
#pragma unroll
        for (int mi = 0; mi < 2; mi++)
#pragma unroll
            for (int ns = 0; ns < 4; ns++) S[mi][ns] = (v4f){0.f, 0.f, 0.f, 0.f};
#pragma unroll
        for (int kk = 0; kk < 2; kk++) {
#pragma unroll
            for (int ns = 0; ns < 4; ns++) {
                v8s kf = *(const v8s*)&Kc[(ns * 16 + m15) * 64 +
                                          (((kk * 4 + quad) ^ sw) * 8)];
#pragma unroll
                for (int mi = 0; mi < 2; mi++)
                    S[mi][ns] =
                        __builtin_amdgcn_mfma_f32_16x16x32_bf16(qa[mi][kk], kf, S[mi][ns], 0, 0, 0);
            }
        }

#pragma unroll
        for (int mi = 0; mi < 2; mi++) {
#pragma unroll
            for (int r = 0; r < 4; r++) {
                int prow = w * 32 + mi * 16 + quad * 4 + r;
                float e0 = __builtin_amdgcn_exp2f(S[mi][0][r]);
                float e1 = __builtin_amdgcn_exp2f(S[mi][1][r]);
                float e2 = __builtin_amdgcn_exp2f(S[mi][2][r]);
                float e3 = __builtin_amdgcn_exp2f(S[mi][3][r]);
                uint2 pk;
                pk.x = pk2bf(e0, e1);
                pk.y = pk2bf(e2, e3);
                *(uint2*)&PQ[prow * 72 + 4 * m15] = pk;
            }
        }

#pragma unroll
        for (int kk = 0; kk < 2; kk++) {
            v8s a0 = *(const v8s*)&PQ[(w * 32 + 0 * 16 + m15) * 72 + kk * 32 + quad * 8];
            v8s a1 = *(const v8s*)&PQ[(w * 32 + 1 * 16 + m15) * 72 + kk * 32 + quad * 8];
            lacc[0] = __builtin_amdgcn_mfma_f32_16x16x32_bf16(a0, ones, lacc[0], 0, 0, 0);
            lacc[1] = __builtin_amdgcn_mfma_f32_16x16x32_bf16(a1, ones, lacc[1], 0, 0, 0);
#pragma unroll
            for (int db = 0; db < 4; db++) {
                v8s vf = *(const v8s*)&Vc[(db * 16 + m15) * 64 +
                                          (((kk * 4 + quad) ^ sw) * 8)];
                O[0][db] = __builtin_amdgcn_mfma_f32_16x16x32_bf16(a0, vf, O[0][db], 0, 0, 0);
                O[1][db] = __builtin_amdgcn_mfma_f32_16x16x32_bf16(a1, vf, O[1][db], 0, 0, 0);
            }
        }
        __syncthreads();
    }

#pragma unroll
    for (int mi = 0; mi < 2; mi++) {
#pragma unroll
        for (int r = 0; r < 4; r++) {
            float inv = 1.f / lacc[mi][r];
            int row = q0 + w * 32 + mi * 16 + quad * 4 + r;
#pragma unroll
            for (int db = 0; db < 4; db++) {
                X[((size_t)(b * LLC + row)) * D_MODELC + hd + db * 16 + m15] =
                    f2bf(O[mi][db][r] * inv);
            }
        }
    }
}

extern "C" void kernel_launch(void* const* d_in, const int* in_sizes, int n_in,
                              void* d_out, int out_size, void* d_ws, size_t ws_size,
                              hipStream_t stream) {
    const float* q = (const float*)d_in[0];
    const float* k = (const float*)d_in[1];
    const float* v = (const float*)d_in[2];
    const float* w_q = (const float*)d_in[3];
    const float* b_q = (const float*)d_in[4];
    const float* w_k = (const float*)d_in[5];
    const float* b_k = (const float*)d_in[6];
    const float* w_v = (const float*)d_in[7];
    const float* b_v = (const float*)d_in[8];
    const float* w_o = (const float*)d_in[9];
    const float* b_o = (const float*)d_in[10];

    const size_t elems = (size_t)MMC * D_MODELC;  // 4M elems = 8MB bf16
    unsigned short* Qp = (unsigned short*)d_ws;   // X aliases Qp (see attn)
    unsigned short* Kp = Qp + elems;
    unsigned short* Vp = Kp + elems;
    unsigned short* Wt = Vp + elems;  // 4 x 1024x1024 bf16 = 8MB (q,k,v,o)
    unsigned short* X = Qp;
    unsigned short* Vt = (unsigned short*)d_out;  // scratch until final GEMM

    const float QSCALE = 0.125f * 1.44269504088896340736f;  // 1/sqrt(64)*log2(e)

    wtrans<<<dim3(16, 16, 4), 256, 0, stream>>>(w_q, w_k, w_v, w_o, Wt);

    // QKV: 3 segs x 32 m-tiles x 8 n-blocks = 768 blocks, XCD-grouped decode
    gemm_tile<128, 3, true, false><<<768, 256, 0, stream>>>(
        q, k, v, Wt, b_q, b_k, b_v, Qp, Kp, Vp, QSCALE, 1.f, 1.f);

    vtrans<<<dim3(LLC / 64, BBC * N_HEADSC), 256, 0, stream>>>(Vp, Vt);

    attn_mfma<<<dim3(LLC / 128, BBC * N_HEADSC), 256, 0, stream>>>(Qp, Kp, Vt, X);

    // final: 1 seg x 64 m-tiles x 8 n-blocks = 512 blocks
    gemm_tile<64, 1, false, true><<<512, 256, 0, stream>>>(
        X, X, X, Wt + (size_t)3 * D_MODELC * D_MODELC, b_o, b_o, b_o,
        d_out, d_out, d_out, 1.f, 1.f, 1.f);
}